// Round 2
// baseline (320.845 us; speedup 1.0000x reference)
//
#include <hip/hip_runtime.h>

#define G_CONST     9.81f
#define DT_VEL_     0.01f
#define MAX_THRUST_ 39.96f                 // 0.9 * 44.4
#define MAX_ANGLE_  0.5235987755982988f    // 30 deg in rad
#define ALPHA_      0.16666667f            // DT/(TAU+DT) in f32
#define TPB         256
#define DPT         4                      // drones per thread
#define DPB         (TPB * DPT)            // 1024 drones per block

typedef float f4 __attribute__((ext_vector_type(4)));

__device__ __forceinline__ void pid_one(
    const float* rv, const float* mv, const float* pi,
    const float* pe, const float* pd,
    float yaw, float m,
    float& rp0o, float& rp1o, float& th)
{
    const float KP[3] = {2.0f, 2.0f, 4.0f};
    const float KI[3] = {0.5f, 0.5f, 1.0f};
    const float KD[3] = {0.1f, 0.1f, 0.05f};
    float u[3];
#pragma unroll
    for (int c = 0; c < 3; ++c) {
        float err   = rv[c] - mv[c];
        float integ = pi[c] + err * DT_VEL_;
        float d_raw = (err - pe[c]) / DT_VEL_;
        float d     = pd[c] + ALPHA_ * (d_raw - pd[c]);
        float uu    = KP[c] * err + KI[c] * integ + KD[c] * d;
        u[c] = fminf(fmaxf(uu, -6.0f), 6.0f);
    }
    float s, c;
    __sincosf(yaw, &s, &c);
    float rp0 = (s * u[0] - c * u[1]) / G_CONST;
    float rp1 = (c * u[0] + s * u[1]) / G_CONST;
    float mag = sqrtf(rp0 * rp0 + rp1 * rp1);
    float sc  = fminf(MAX_ANGLE_ / (mag + 1e-6f), 1.0f);
    sc = (mag > MAX_ANGLE_) ? sc : 1.0f;
    rp0o = rp0 * sc;
    rp1o = rp1 * sc;
    th = fminf(fmaxf(m * G_CONST + m * u[2], 0.8f * G_CONST * m), MAX_THRUST_);
}

// Load 12 consecutive floats (4 drones x vec3) as 3 aligned nontemporal float4s
// into a register array (constant indices -> SROA keeps it in VGPRs).
__device__ __forceinline__ void load12nt(const float* __restrict__ p, float* d)
{
    const f4* p4 = (const f4*)p;
    f4 a = __builtin_nontemporal_load(p4 + 0);
    f4 b = __builtin_nontemporal_load(p4 + 1);
    f4 c = __builtin_nontemporal_load(p4 + 2);
    d[0]  = a[0]; d[1]  = a[1]; d[2]  = a[2]; d[3]  = a[3];
    d[4]  = b[0]; d[5]  = b[1]; d[6]  = b[2]; d[7]  = b[3];
    d[8]  = c[0]; d[9]  = c[1]; d[10] = c[2]; d[11] = c[3];
}

__global__ __launch_bounds__(TPB) void pos_ctrl_nt(
    const float* __restrict__ ref_ve,
    const float* __restrict__ meas_ve,
    const float* __restrict__ meas_yaw,
    const float* __restrict__ mass,
    const float* __restrict__ pid_int,
    const float* __restrict__ pid_prev_err,
    const float* __restrict__ pid_prev_d,
    float* __restrict__ out,   // fp32: [n*2 rp interleaved][n thrust]
    int n)
{
    const long t    = (long)blockIdx.x * TPB + threadIdx.x;  // global thread id
    const long base = t * DPT;                               // first drone of this thread

    if (base + DPT <= n) {
        // ---- loads: 17 independent nontemporal 16B loads in flight ----
        const size_t g = (size_t)base * 3;   // float offset; byte offset 48*t (16B-aligned)
        float rv[12], mv[12], pi[12], pe[12], pd[12];
        load12nt(ref_ve       + g, rv);
        load12nt(meas_ve      + g, mv);
        load12nt(pid_int      + g, pi);
        load12nt(pid_prev_err + g, pe);
        load12nt(pid_prev_d   + g, pd);
        const f4 yw4 = __builtin_nontemporal_load((const f4*)meas_yaw + t);
        const f4 m4  = __builtin_nontemporal_load((const f4*)mass + t);
        const float yw[4] = {yw4[0], yw4[1], yw4[2], yw4[3]};
        const float mm[4] = {m4[0],  m4[1],  m4[2],  m4[3]};

        // ---- compute 4 drones, fully unrolled ----
        float rp[8], thr[4];
#pragma unroll
        for (int d = 0; d < DPT; ++d) {
            pid_one(&rv[d * 3], &mv[d * 3], &pi[d * 3], &pe[d * 3], &pd[d * 3],
                    yw[d], mm[d], rp[d * 2], rp[d * 2 + 1], thr[d]);
        }

        // ---- stores: nontemporal; rp = 2x float4 (byte 32*t, aligned); thrust = 1x float4 ----
        f4* outrp = (f4*)(out + (size_t)base * 2);
        f4 o0 = {rp[0], rp[1], rp[2], rp[3]};
        f4 o1 = {rp[4], rp[5], rp[6], rp[7]};
        __builtin_nontemporal_store(o0, outrp + 0);
        __builtin_nontemporal_store(o1, outrp + 1);
        float* thrp = out + 2 * (size_t)n + base;
        if ((n & 3) == 0) {   // block-uniform; guarantees 16B alignment of thrust slab
            f4 tv = {thr[0], thr[1], thr[2], thr[3]};
            __builtin_nontemporal_store(tv, (f4*)thrp);
        } else {
#pragma unroll
            for (int d = 0; d < DPT; ++d) thrp[d] = thr[d];
        }
    } else {
        // tail: per-drone scalar path (never taken for n % 1024 == 0)
#pragma unroll
        for (int d = 0; d < DPT; ++d) {
            const long i = base + d;
            if (i < n) {
                const size_t k = (size_t)i * 3;
                float rp0, rp1, th;
                pid_one(&ref_ve[k], &meas_ve[k], &pid_int[k], &pid_prev_err[k],
                        &pid_prev_d[k], meas_yaw[i], mass[i], rp0, rp1, th);
                out[(size_t)i * 2 + 0] = rp0;
                out[(size_t)i * 2 + 1] = rp1;
                out[2 * (size_t)n + i] = th;
            }
        }
    }
}

extern "C" void kernel_launch(void* const* d_in, const int* in_sizes, int n_in,
                              void* d_out, int out_size, void* d_ws, size_t ws_size,
                              hipStream_t stream) {
    const float* ref_ve       = (const float*)d_in[0];
    const float* meas_ve      = (const float*)d_in[1];
    const float* meas_yaw     = (const float*)d_in[2];
    const float* mass         = (const float*)d_in[3];
    const float* pid_int      = (const float*)d_in[4];
    const float* pid_prev_err = (const float*)d_in[5];
    const float* pid_prev_d   = (const float*)d_in[6];
    float* out = (float*)d_out;
    const int n = in_sizes[2];  // meas_yaw element count == N

    const int grid = (n + DPB - 1) / DPB;
    pos_ctrl_nt<<<grid, TPB, 0, stream>>>(
        ref_ve, meas_ve, meas_yaw, mass, pid_int, pid_prev_err, pid_prev_d, out, n);
}

// Round 3
// 270.357 us; speedup vs baseline: 1.1867x; 1.1867x over previous
//
#include <hip/hip_runtime.h>

#define G_CONST     9.81f
#define DT_VEL_     0.01f
#define MAX_THRUST_ 39.96f                 // 0.9 * 44.4
#define MAX_ANGLE_  0.5235987755982988f    // 30 deg in rad
#define ALPHA_      0.16666667f            // DT/(TAU+DT) in f32
#define TILE        256

// Roofline note (session r0-r2): three structurally different kernels
// (LDS-staged / reg-tiled x4 / reg-tiled+NT) all pin the CU-side read rate
// at 2.60-2.69 TB/s while HBM traffic varies 193-410 MB. The limiter is the
// read-direction L2-miss/fabric fill path, not HBM and not latency.
// Floor = 285 MB reads / 2.65 TB/s ~= 106 us; this kernel measures ~106 us.

__device__ __forceinline__ void pid_one(
    const float* rv, const float* mv, const float* pi,
    const float* pe, const float* pd,
    float yaw, float m,
    float& rp0o, float& rp1o, float& th)
{
    const float KP[3] = {2.0f, 2.0f, 4.0f};
    const float KI[3] = {0.5f, 0.5f, 1.0f};
    const float KD[3] = {0.1f, 0.1f, 0.05f};
    float u[3];
#pragma unroll
    for (int c = 0; c < 3; ++c) {
        float err   = rv[c] - mv[c];
        float integ = pi[c] + err * DT_VEL_;
        float d_raw = (err - pe[c]) / DT_VEL_;
        float d     = pd[c] + ALPHA_ * (d_raw - pd[c]);
        float uu    = KP[c] * err + KI[c] * integ + KD[c] * d;
        u[c] = fminf(fmaxf(uu, -6.0f), 6.0f);
    }
    float s, c;
    __sincosf(yaw, &s, &c);
    float rp0 = (s * u[0] - c * u[1]) / G_CONST;
    float rp1 = (c * u[0] + s * u[1]) / G_CONST;
    float mag = sqrtf(rp0 * rp0 + rp1 * rp1);
    float sc  = fminf(MAX_ANGLE_ / (mag + 1e-6f), 1.0f);
    sc = (mag > MAX_ANGLE_) ? sc : 1.0f;
    rp0o = rp0 * sc;
    rp1o = rp1 * sc;
    th = fminf(fmaxf(m * G_CONST + m * u[2], 0.8f * G_CONST * m), MAX_THRUST_);
}

__global__ __launch_bounds__(256) void pos_ctrl_lds(
    const float* __restrict__ ref_ve,
    const float* __restrict__ meas_ve,
    const float* __restrict__ meas_yaw,
    const float* __restrict__ mass,
    const float* __restrict__ pid_int,
    const float* __restrict__ pid_prev_err,
    const float* __restrict__ pid_prev_d,
    float* __restrict__ out,   // fp32: [n*2 rp interleaved][n thrust]
    int n)
{
    // 5 x 3 KB = 15 KB LDS -> 8 blocks/CU (wave-capped), 100% occupancy
    __shared__ float s_rv[TILE * 3];
    __shared__ float s_mv[TILE * 3];
    __shared__ float s_pi[TILE * 3];
    __shared__ float s_pe[TILE * 3];
    __shared__ float s_pd[TILE * 3];

    const int  tid = threadIdx.x;
    const long d0  = (long)blockIdx.x * TILE;

    if (d0 + TILE <= n) {
        // scalar per-drone inputs: stride-4 coalesced
        const float yw = meas_yaw[d0 + tid];
        const float m  = mass[d0 + tid];

        // Stage 5 vec3 arrays: 192 float4 per array, lane-contiguous (1024 B/instr)
        if (tid < (3 * TILE) / 4) {   // 192 threads
            const size_t g = (size_t)d0 * 3;  // float offset of tile; 3072B-aligned
            float4 v0 = ((const float4*)(ref_ve       + g))[tid];
            float4 v1 = ((const float4*)(meas_ve     + g))[tid];
            float4 v2 = ((const float4*)(pid_int     + g))[tid];
            float4 v3 = ((const float4*)(pid_prev_err + g))[tid];
            float4 v4 = ((const float4*)(pid_prev_d  + g))[tid];
            ((float4*)s_rv)[tid] = v0;
            ((float4*)s_mv)[tid] = v1;
            ((float4*)s_pi)[tid] = v2;
            ((float4*)s_pe)[tid] = v3;
            ((float4*)s_pd)[tid] = v4;
        }
        __syncthreads();

        const int k = tid * 3;  // LDS read at 12B stride: <=2-way bank alias (free)
        float rp0, rp1, thr;
        pid_one(&s_rv[k], &s_mv[k], &s_pi[k], &s_pe[k], &s_pd[k],
                yw, m, rp0, rp1, thr);

        ((float2*)out)[d0 + tid] = make_float2(rp0, rp1);  // stride-8, contiguous
        out[2 * (size_t)n + d0 + tid] = thr;               // stride-4, contiguous
    } else if (d0 + tid < n) {
        // tail tile (block-uniform branch; no __syncthreads on this path)
        const long i = d0 + tid;
        const size_t k = (size_t)i * 3;
        float rp0, rp1, thr;
        pid_one(&ref_ve[k], &meas_ve[k], &pid_int[k], &pid_prev_err[k], &pid_prev_d[k],
                meas_yaw[i], mass[i], rp0, rp1, thr);
        out[(size_t)i * 2 + 0] = rp0;
        out[(size_t)i * 2 + 1] = rp1;
        out[2 * (size_t)n + i] = thr;
    }
}

extern "C" void kernel_launch(void* const* d_in, const int* in_sizes, int n_in,
                              void* d_out, int out_size, void* d_ws, size_t ws_size,
                              hipStream_t stream) {
    const float* ref_ve       = (const float*)d_in[0];
    const float* meas_ve      = (const float*)d_in[1];
    const float* meas_yaw     = (const float*)d_in[2];
    const float* mass         = (const float*)d_in[3];
    const float* pid_int      = (const float*)d_in[4];
    const float* pid_prev_err = (const float*)d_in[5];
    const float* pid_prev_d   = (const float*)d_in[6];
    float* out = (float*)d_out;
    const int n = in_sizes[2];  // meas_yaw element count == N

    const int grid = (n + TILE - 1) / TILE;
    pos_ctrl_lds<<<grid, TILE, 0, stream>>>(
        ref_ve, meas_ve, meas_yaw, mass, pid_int, pid_prev_err, pid_prev_d, out, n);
}